// Round 12
// baseline (434.608 us; speedup 1.0000x reference)
//
#include <hip/hip_runtime.h>
#include <hip/hip_bf16.h>

#define B_   128
#define S_   512
#define H_   128
#define G_   512   // 4*H
#define EMB_ 128
#define NL_  9

typedef __attribute__((ext_vector_type(8))) short bf16x8;
typedef __attribute__((ext_vector_type(4))) short bf16x4;
typedef __attribute__((ext_vector_type(4))) float f32x4;
typedef unsigned short ushort_t;

// LDS-only barrier: vmem ops stay in flight across it.
__device__ __forceinline__ void wg_bar() {
    asm volatile("s_waitcnt lgkmcnt(0)\n\ts_barrier" ::: "memory");
}

__device__ __forceinline__ float bfbits2f(short s) {
    unsigned int u = ((unsigned int)(unsigned short)s) << 16;
    return __builtin_bit_cast(float, u);
}
__device__ __forceinline__ short f2bf(float f) {
    unsigned int u = __builtin_bit_cast(unsigned int, f);
    u += 0x7FFFu + ((u >> 16) & 1u);
    return (short)(u >> 16);
}
__device__ __forceinline__ unsigned int pack2(float lo, float hi) {
    return (unsigned int)(unsigned short)f2bf(lo) | ((unsigned int)(unsigned short)f2bf(hi) << 16);
}
// raw transcendentals: avoid libm guard expansions.
__device__ __forceinline__ float exp2_(float x) {
    float r; asm("v_exp_f32 %0, %1" : "=v"(r) : "v"(x)); return r;
}
__device__ __forceinline__ float log2_(float x) {
    float r; asm("v_log_f32 %0, %1" : "=v"(r) : "v"(x)); return r;
}
__device__ __forceinline__ float max3_(float a, float b, float c) {
    float r; asm("v_max3_f32 %0, %1, %2, %3" : "=v"(r) : "v"(a), "v"(b), "v"(c)); return r;
}
__device__ __forceinline__ float tanh_(float x) {
    return 1.f - 2.f * __builtin_amdgcn_rcpf(1.f + exp2_(2.8853900817779268f * x));
}

// ---------------------------------------------------------------------------
// prep2: weights only (68 blocks, ~5 us). r9-verified + zeroes the crf
// completion counter each launch (graph-replay-safe).
// ---------------------------------------------------------------------------
__global__ __launch_bounds__(256)
void prep2_kernel(const float* __restrict__ w_ih_f, const float* __restrict__ w_ih_b,
                  const float* __restrict__ b_ih_f, const float* __restrict__ b_hh_f,
                  const float* __restrict__ b_ih_b, const float* __restrict__ b_hh_b,
                  ushort_t* __restrict__ wihPack, float* __restrict__ biasPack,
                  unsigned int* __restrict__ ctr)
{
    const int bid = blockIdx.x, tid = threadIdx.x;
    if (bid < 64) {
        int f = bid * 256 + tid;                  // 0..16383
        int lane = f & 63;
        int nt  = (f >> 6) & 3;
        int ks  = (f >> 8) & 3;
        int wv8 = (f >> 10) & 7;
        int dirq = (f >> 13) & 1;
        int n16 = lane & 15, quad = lane >> 4;
        const float* w = dirq ? w_ih_b : w_ih_f;
        int col = nt * 128 + wv8 * 16 + n16;
        const float* p = w + col * EMB_ + ks * 32 + quad * 8;
        bf16x8 r;
#pragma unroll
        for (int j = 0; j < 8; j++) r[j] = f2bf(p[j]);
        size_t addr = ((size_t)dirq * 8192 + wv8 * 1024 + ks * 256 + nt * 64 + lane) * 8;
        *(bf16x8*)(wihPack + addr) = r;
    } else {
        if (bid == 64 && tid == 0) *ctr = 0u;
        int idx = (bid - 64) * 256 + tid;
        if (idx < 1024) {
            int nt  = idx & 3;
            int n16 = (idx >> 2) & 15;
            int wv8 = (idx >> 6) & 7;
            int dirq = (idx >> 9) & 1;
            const float* bi = dirq ? b_ih_b : b_ih_f;
            const float* bh = dirq ? b_hh_b : b_hh_f;
            int col = nt * 128 + wv8 * 16 + n16;
            biasPack[idx] = bi[col] + bh[col];
        }
    }
}

// ---------------------------------------------------------------------------
// xw2: slim xw pre-pass. Unchanged from r9 (verified).
// Output layout (ushorts): xw[((dir*128 + b)*512 + t)*512 + u*4 + nt].
// ---------------------------------------------------------------------------
__global__ __launch_bounds__(512, 1)
void xw2_kernel(const int* __restrict__ seq, const float* __restrict__ emb,
                const ushort_t* __restrict__ wihPack, const float* __restrict__ biasPack,
                ushort_t* __restrict__ xw)
{
    __shared__ bf16x8 ldsX[64 * 17];

    const int tid  = threadIdx.x;
    const int wv   = tid >> 6;
    const int lane = tid & 63;
    const int n16  = tid & 15;
    const int quad = (tid & 63) >> 4;
    const int dir  = blockIdx.x >> 10;
    const int rem  = blockIdx.x & 1023;
    const int pair = rem >> 4;
    const int tb   = (rem & 15) * 32;

    // stage 64 rows: rows 0..31 chain0 (b=2*pair) t=tb..tb+31, rows 32..63 chain1
    {
        int row = tid >> 3, part = tid & 7;
        int b = 2 * pair + (row >> 5);
        int t = tb + (row & 31);
        int tok = seq[b * S_ + t];
        const float* ep = emb + (size_t)tok * EMB_ + part * 16;
        int rt = row >> 4, rr = row & 15;
#pragma unroll
        for (int h = 0; h < 2; h++) {
            float4 a = *(const float4*)(ep + h * 8);
            float4 b4 = *(const float4*)(ep + h * 8 + 4);
            bf16x8 fr;
            fr[0] = f2bf(a.x); fr[1] = f2bf(a.y); fr[2] = f2bf(a.z); fr[3] = f2bf(a.w);
            fr[4] = f2bf(b4.x); fr[5] = f2bf(b4.y); fr[6] = f2bf(b4.z); fr[7] = f2bf(b4.w);
            ldsX[(rt * 16 + part * 2 + h) * 17 + rr] = fr;
        }
    }

    // pre-packed weight fragments + fused biases
    bf16x8 bfrag[4][4];
    float  bias[4];
    {
        const ushort_t* wb = wihPack + ((size_t)dir * 8192 + (size_t)wv * 1024 + lane) * 8;
#pragma unroll
        for (int nt = 0; nt < 4; nt++) {
            bias[nt] = biasPack[((dir * 8 + wv) * 16 + n16) * 4 + nt];
#pragma unroll
            for (int ks = 0; ks < 4; ks++)
                bfrag[nt][ks] = *(const bf16x8*)(wb + (ks * 256 + nt * 64) * 8);
        }
    }
    __syncthreads();

    const size_t plane0 = (size_t)(dir * 128 + 2 * pair);

#pragma unroll
    for (int half = 0; half < 2; half++) {
        // chain0 tile = half, chain1 tile = half+2
        f32x4 accA[4], accB[4];
        bf16x8 afA[4], afB[4];
#pragma unroll
        for (int ks = 0; ks < 4; ks++) {
            afA[ks] = ldsX[(half * 16 + ks * 4 + quad) * 17 + n16];
            afB[ks] = ldsX[((half + 2) * 16 + ks * 4 + quad) * 17 + n16];
        }
#pragma unroll
        for (int nt = 0; nt < 4; nt++) {
            f32x4 a = {bias[nt], bias[nt], bias[nt], bias[nt]};
            accA[nt] = a; accB[nt] = a;
#pragma unroll
            for (int ks = 0; ks < 4; ks++) {
                accA[nt] = __builtin_amdgcn_mfma_f32_16x16x32_bf16(afA[ks], bfrag[nt][ks], accA[nt], 0, 0, 0);
                accB[nt] = __builtin_amdgcn_mfma_f32_16x16x32_bf16(afB[ks], bfrag[nt][ks], accB[nt], 0, 0, 0);
            }
        }
        const int u = wv * 16 + n16;
#pragma unroll
        for (int r = 0; r < 4; r++) {
            int t = tb + half * 16 + quad * 4 + r;
            int2 iv0, iv1;
            iv0.x = (int)pack2(accA[0][r], accA[1][r]);
            iv0.y = (int)pack2(accA[2][r], accA[3][r]);
            iv1.x = (int)pack2(accB[0][r], accB[1][r]);
            iv1.y = (int)pack2(accB[2][r], accB[3][r]);
            *(int2*)(xw + ((plane0 * S_ + t) * 128 + u) * 4) = iv0;
            *(int2*)(xw + (((plane0 + 1) * S_ + t) * 128 + u) * 4) = iv1;
        }
    }
}

// ---------------------------------------------------------------------------
// Recurrent LSTM: 8 waves/chain (r11-verified structure) + SPLIT MFMA
// accumulation chains: each gate = (af0->af1 chain) + (af2->af3 chain),
// combined by one f32 add. Halves the dependent-MFMA latency on the
// barrier-to-barrier critical path (~4x35cy -> ~2x35cy + add).
// ---------------------------------------------------------------------------
#define STEPK(k)                                                                   \
  {                                                                                \
    if ((k) == 0 && s4 == 0 && m < 31) {                                           \
      const ushort_t* gp = xwp + (size_t)(dir ? (S_ - 32 - m16) : (m16 + 16)) * 512; \
      sA = *(const int4*)(gp + tid * 8);                                           \
      sB = *(const int4*)(gp + 4096 + tid * 8);                                    \
    }                                                                              \
    bf16x8 af0 = hbuf[(k) & 1][0 * 4 + quad];                                      \
    bf16x8 af1 = hbuf[(k) & 1][1 * 4 + quad];                                      \
    bf16x8 af2 = hbuf[(k) & 1][2 * 4 + quad];                                      \
    bf16x8 af3 = hbuf[(k) & 1][3 * 4 + quad];                                      \
    const int KE = s4x4 + (k);                                                     \
    const int slot = dir ? (15 - KE) : KE;                                         \
    bf16x4 xvg = *(const bf16x4*)(xwS + (m & 1) * 8192 + slot * 512 + uu * 4);     \
    if ((k) == 0 && s4 == 2 && m < 31) {                                           \
      int4* dst = (int4*)(xwL + (((m & 1) ^ 1) * 1024));                           \
      dst[tid] = sA; dst[512 + tid] = sB;                                          \
    }                                                                              \
    if ((k) == 1 && s4 == 0 && m >= 1 && wv == 7 && lane < 36) {                   \
      int a0 = dir ? (S_ - m16) : (m16 - 16);                                      \
      float4 fv = *(const float4*)(emL + (a0 & 31) * 9 + lane * 4);                \
      *(float4*)(emdir + (size_t)b * (S_ * NL_) + a0 * NL_ + lane * 4) = fv;       \
    }                                                                              \
    f32x4 aX0 = __builtin_amdgcn_mfma_f32_16x16x32_bf16(af0, bfrag[0][0], ZACC, 0, 0, 0); \
    f32x4 aX1 = __builtin_amdgcn_mfma_f32_16x16x32_bf16(af0, bfrag[1][0], ZACC, 0, 0, 0); \
    f32x4 aX2 = __builtin_amdgcn_mfma_f32_16x16x32_bf16(af0, bfrag[2][0], ZACC, 0, 0, 0); \
    f32x4 aX3 = __builtin_amdgcn_mfma_f32_16x16x32_bf16(af0, bfrag[3][0], ZACC, 0, 0, 0); \
    f32x4 aY0 = __builtin_amdgcn_mfma_f32_16x16x32_bf16(af2, bfrag[0][2], ZACC, 0, 0, 0); \
    f32x4 aY1 = __builtin_amdgcn_mfma_f32_16x16x32_bf16(af2, bfrag[1][2], ZACC, 0, 0, 0); \
    f32x4 aY2 = __builtin_amdgcn_mfma_f32_16x16x32_bf16(af2, bfrag[2][2], ZACC, 0, 0, 0); \
    f32x4 aY3 = __builtin_amdgcn_mfma_f32_16x16x32_bf16(af2, bfrag[3][2], ZACC, 0, 0, 0); \
    aX0 = __builtin_amdgcn_mfma_f32_16x16x32_bf16(af1, bfrag[0][1], aX0, 0, 0, 0); \
    aX1 = __builtin_amdgcn_mfma_f32_16x16x32_bf16(af1, bfrag[1][1], aX1, 0, 0, 0); \
    aX2 = __builtin_amdgcn_mfma_f32_16x16x32_bf16(af1, bfrag[2][1], aX2, 0, 0, 0); \
    aX3 = __builtin_amdgcn_mfma_f32_16x16x32_bf16(af1, bfrag[3][1], aX3, 0, 0, 0); \
    aY0 = __builtin_amdgcn_mfma_f32_16x16x32_bf16(af3, bfrag[0][3], aY0, 0, 0, 0); \
    aY1 = __builtin_amdgcn_mfma_f32_16x16x32_bf16(af3, bfrag[1][3], aY1, 0, 0, 0); \
    aY2 = __builtin_amdgcn_mfma_f32_16x16x32_bf16(af3, bfrag[2][3], aY2, 0, 0, 0); \
    aY3 = __builtin_amdgcn_mfma_f32_16x16x32_bf16(af3, bfrag[3][3], aY3, 0, 0, 0); \
    {                                                                              \
      float gi = (aX0[0] + aY0[0]) + bfbits2f(xvg[0]);                             \
      float gf = (aX1[0] + aY1[0]) + bfbits2f(xvg[1]);                             \
      float gg = (aX2[0] + aY2[0]) + bfbits2f(xvg[2]);                             \
      float go = (aX3[0] + aY3[0]) + bfbits2f(xvg[3]);                             \
      float Af = exp2_(-1.4426950408889634f * gf);                                 \
      float Bi = exp2_(-1.4426950408889634f * gi);                                 \
      float Cg = exp2_(2.8853900817779268f * gg);                                  \
      float Fo = exp2_(-1.4426950408889634f * go);                                 \
      float oA = 1.f + Af, oB = 1.f + Bi, oC = 1.f + Cg;                           \
      float P = oB * oC;                                                           \
      float numer = cst * P + oA * (Cg - 1.f);                                     \
      cst = numer * __builtin_amdgcn_rcpf(oA * P);                                 \
      float hv = tanh_(cst) * __builtin_amdgcn_rcpf(1.f + Fo);                     \
      if (quad == 0) *(((k) & 1) ? hw0 : hw1) = f2bf(hv);                          \
    }                                                                              \
    if (wv == 0) {                                                                 \
      f32x4 eX = __builtin_amdgcn_mfma_f32_16x16x32_bf16(af0, bfragE[0], ZACC, 0, 0, 0); \
      f32x4 eY = __builtin_amdgcn_mfma_f32_16x16x32_bf16(af2, bfragE[2], ZACC, 0, 0, 0); \
      eX = __builtin_amdgcn_mfma_f32_16x16x32_bf16(af1, bfragE[1], eX, 0, 0, 0);   \
      eY = __builtin_amdgcn_mfma_f32_16x16x32_bf16(af3, bfragE[3], eY, 0, 0, 0);   \
      if (quad == 0 && n16 < NL_ && (m16 + KE) >= 1) {                             \
        int tprev = dir ? (S_ - (m16 + KE)) : (m16 + KE - 1);                      \
        emL[(tprev & 31) * 9 + n16] = eX[0] + eY[0];                               \
      }                                                                            \
    }                                                                              \
    wg_bar();                                                                      \
  }

__global__ __launch_bounds__(512, 1)
void lstm_kernel(const ushort_t* __restrict__ xw,
                 const float* __restrict__ w_hh_f, const float* __restrict__ w_hh_b,
                 const float* __restrict__ w_out,
                 float* __restrict__ em_f, float* __restrict__ em_b)
{
    __shared__ bf16x8 xwL[2 * 1024];           // 32 KB: [buf][t*512 + u*4 + nt] ushorts
    __shared__ bf16x8 hbuf[2][16];             // 512 B, double-buffered h (128 bf16/buf)
    __shared__ __align__(16) float emL[32 * NL_];  // 1152 B: [slot][label]

    const int tid  = threadIdx.x;
    const int wv   = tid >> 6;                 // 8 waves
    const int lane = tid & 63;
    const int n16  = tid & 15;
    const int quad = (tid & 63) >> 4;
    const int dir  = blockIdx.x >> 7;
    const int b    = blockIdx.x & 127;

    const int uu = wv * 16 + n16;              // unit owned by this lane (quads redundant)

    // per-lane h-write pointers (buf0/buf1); writer is quad 0
    short* hw0 = ((short*)hbuf) + uu;
    short* hw1 = ((short*)hbuf) + 128 + uu;
    const short* xwS = (const short*)xwL;

    const f32x4 ZACC = {0.f, 0.f, 0.f, 0.f};

    const float* whh = dir ? w_hh_b : w_hh_f;
    float* emdir = dir ? em_b : em_f;

    // W_hh fragments: bfrag[gate][ks]; gate col = nt*128 + wv*16 + n16
    bf16x8 bfrag[4][4];
#pragma unroll
    for (int nt = 0; nt < 4; nt++) {
        int col = nt * 128 + wv * 16 + n16;
#pragma unroll
        for (int ks = 0; ks < 4; ks++) {
            const float* p = whh + col * H_ + ks * 32 + quad * 8;
            bf16x8 fr;
#pragma unroll
            for (int j = 0; j < 8; j++) fr[j] = f2bf(p[j]);
            bfrag[nt][ks] = fr;
        }
    }
    bf16x8 bfragE[4];
#pragma unroll
    for (int ks = 0; ks < 4; ks++) {
        bf16x8 fr = {0, 0, 0, 0, 0, 0, 0, 0};
        if (n16 < NL_) {
            const float* p = w_out + n16 * 256 + dir * 128 + ks * 32 + quad * 8;
#pragma unroll
            for (int j = 0; j < 8; j++) fr[j] = f2bf(p[j]);
        }
        bfragE[ks] = fr;
    }

    if (tid < 64) ((int*)hbuf)[tid] = 0;   // zero h buffer 0 (256 B)

    const ushort_t* xwp = xw + (size_t)(dir * 128 + b) * ((size_t)S_ * 512);
    // pre-stage block 0 (16 KB): 2 x int4 per thread
    {
        const ushort_t* gp = xwp + (size_t)(dir ? (S_ - 16) : 0) * 512;
        int4 a0 = *(const int4*)(gp + tid * 8);
        int4 a1 = *(const int4*)(gp + 4096 + tid * 8);
        int4* dst = (int4*)xwL;
        dst[tid] = a0; dst[512 + tid] = a1;
    }

    float cst = 0.f;
    int4 sA, sB;
    wg_bar();

#pragma unroll 1
    for (int m = 0; m < 32; m++) {
        const int m16 = m << 4;
#pragma unroll 1
        for (int s4 = 0; s4 < 4; s4++) {
            const int s4x4 = s4 << 2;
            STEPK(0) STEPK(1) STEPK(2) STEPK(3)
        }
    }

    // final emission (h after step 512, in buf0), then tail flush
    if (wv == 0) {
        bf16x8 af0 = hbuf[0][0 * 4 + quad];
        bf16x8 af1 = hbuf[0][1 * 4 + quad];
        bf16x8 af2 = hbuf[0][2 * 4 + quad];
        bf16x8 af3 = hbuf[0][3 * 4 + quad];
        f32x4 eX = __builtin_amdgcn_mfma_f32_16x16x32_bf16(af0, bfragE[0], ZACC, 0, 0, 0);
        f32x4 eY = __builtin_amdgcn_mfma_f32_16x16x32_bf16(af2, bfragE[2], ZACC, 0, 0, 0);
        eX = __builtin_amdgcn_mfma_f32_16x16x32_bf16(af1, bfragE[1], eX, 0, 0, 0);
        eY = __builtin_amdgcn_mfma_f32_16x16x32_bf16(af3, bfragE[3], eY, 0, 0, 0);
        if (quad == 0 && n16 < NL_) {
            int tprev = dir ? 0 : (S_ - 1);
            emL[(tprev & 31) * 9 + n16] = eX[0] + eY[0];
        }
    }
    wg_bar();
    if (wv == 7 && lane < 36) {
        int a0 = dir ? 0 : (S_ - 16);
        float4 fv = *(const float4*)(emL + (a0 & 31) * 9 + lane * 4);
        *(float4*)(emdir + (size_t)b * (S_ * NL_) + a0 * NL_ + lane * 4) = fv;
    }
}

// ---------------------------------------------------------------------------
// CRF with chunked parallel scan + in-kernel final reduction (last-block
// pattern): each block writes partial[b], threadfences, bumps a device-scope
// counter; the 128th block wave-reduces the partials into out[0]. Counter is
// zeroed by prep2 each launch; the %128 check also tolerates stale values.
// ---------------------------------------------------------------------------
__global__ __launch_bounds__(640, 1)
void crf_kernel(const int* __restrict__ seq, const int* __restrict__ lab,
                const float* __restrict__ em_f, const float* __restrict__ em_b,
                const float* __restrict__ b_out,
                const float* __restrict__ start_t, const float* __restrict__ end_t,
                const float* __restrict__ trans, float* __restrict__ partial,
                unsigned int* __restrict__ ctr, float* __restrict__ out)
{
    __shared__ float emS[S_ * NL_];
    __shared__ float transS[NL_ * NL_];
    __shared__ float stS[NL_], enS[NL_];
    __shared__ unsigned char maskS[S_];
    __shared__ float MS[7 * 81];
    __shared__ float vS[NL_];
    __shared__ float redw[10];
    __shared__ int   redl[10];
    __shared__ unsigned int lastS;

    const int b = blockIdx.x, tid = threadIdx.x;
    const size_t base = (size_t)b * S_ * NL_;
    const float L2E = 1.4426950408889634f, LN2 = 0.6931471805599453f;

    for (int q = tid; q < S_ * NL_; q += 640)
        emS[q] = em_f[base + q] + em_b[base + q] + b_out[q % NL_];
    if (tid < NL_ * NL_) transS[tid] = trans[tid];
    if (tid < NL_) { stS[tid] = start_t[tid]; enS[tid] = end_t[tid]; }
    if (tid < S_) maskS[tid] = (seq[b * S_ + tid] != 0);
    __syncthreads();

    float np = 0.f; int myc = 0;
    if (tid < S_) {
        myc = maskS[tid];
        if (tid >= 1 && maskS[tid]) {
            int lp = lab[b * S_ + tid - 1], lc = lab[b * S_ + tid];
            np = transS[lp * NL_ + lc] + emS[tid * NL_ + lc];
        }
    }
#pragma unroll
    for (int off = 32; off; off >>= 1) {
        np  += __shfl_down(np, off, 64);
        myc += __shfl_down(myc, off, 64);
    }
    if ((tid & 63) == 0) { redw[tid >> 6] = np; redl[tid >> 6] = myc; }

    const int w = tid >> 6, l = tid & 63;
    const int lg = l / 9;
    const int g  = w * 7 + lg;
    const bool sact = (lg < 7) && (g < 64);
    const int jj = sact ? (l - lg * 9) : 0;
    const int gb = sact ? lg * 9 : 0;
    float Tc[NL_];
#pragma unroll
    for (int i = 0; i < NL_; i++) Tc[i] = transS[i * NL_ + jj];
    float sc; int tbeg, tend, cN = 0, iN = 0;
    if (sact && g == 0) {
        sc = stS[jj] + emS[jj];
        tbeg = 1; tend = 64;
    } else if (sact) {
        cN = 1 + (g - 1) / 9; iN = (g - 1) % 9;
        sc = (jj == iN) ? 0.f : -1e30f;
        tbeg = cN * 64; tend = tbeg + 64;
    } else {
        sc = -1e30f; tbeg = 448; tend = 512;
    }
    for (int t = tbeg; t < tend; t++) {
        float emv = emS[t * NL_ + jj];
        float a[NL_];
#pragma unroll
        for (int i = 0; i < NL_; i++) a[i] = __shfl(sc, gb + i, 64) + Tc[i];
        float m = max3_(max3_(a[0], a[1], a[2]), max3_(a[3], a[4], a[5]),
                        max3_(a[6], a[7], a[8]));
        float e[NL_];
#pragma unroll
        for (int i = 0; i < NL_; i++) e[i] = exp2_((a[i] - m) * L2E);
        float sum = ((e[0] + e[1]) + (e[2] + e[3])) + ((e[4] + e[5]) + (e[6] + e[7])) + e[8];
        float nxt = emv + m + LN2 * log2_(sum);
        sc = maskS[t] ? nxt : sc;
    }
    if (sact) {
        if (g == 0) vS[jj] = sc;
        else MS[(cN - 1) * 81 + iN * NL_ + jj] = sc;
    }
    __syncthreads();

    if (tid < 64) {
        const int j = (tid < NL_) ? tid : (NL_ - 1);
        float v = vS[j];
        for (int c = 1; c < 8; c++) {
            float a[NL_];
#pragma unroll
            for (int i = 0; i < NL_; i++)
                a[i] = __shfl(v, i, 64) + MS[(c - 1) * 81 + i * NL_ + j];
            float m = max3_(max3_(a[0], a[1], a[2]), max3_(a[3], a[4], a[5]),
                            max3_(a[6], a[7], a[8]));
            float e[NL_];
#pragma unroll
            for (int i = 0; i < NL_; i++) e[i] = exp2_((a[i] - m) * L2E);
            float sum = ((e[0] + e[1]) + (e[2] + e[3])) + ((e[4] + e[5]) + (e[6] + e[7])) + e[8];
            v = m + LN2 * log2_(sum);
        }
        v += enS[j];
        float mm = -1e30f, av[NL_];
#pragma unroll
        for (int i = 0; i < NL_; i++) { float vi = __shfl(v, i, 64); av[i] = vi; mm = fmaxf(mm, vi); }
        float ss = 0.f;
#pragma unroll
        for (int i = 0; i < NL_; i++) ss += exp2_((av[i] - mm) * L2E);
        if (tid == 0) {
            float num = 0.f; int len = 0;
#pragma unroll
            for (int ww = 0; ww < 10; ww++) { num += redw[ww]; len += redl[ww]; }
            int l0 = lab[b * S_];
            int ll = lab[b * S_ + len - 1];
            num += stS[l0] + emS[l0] + enS[ll];
            partial[b] = (mm + LN2 * log2_(ss)) - num;
        }
    }
    __syncthreads();

    // last-block final reduction
    if (tid == 0) {
        __threadfence();
        unsigned int v = atomicAdd(ctr, 1u);
        lastS = ((v % (unsigned int)B_) == (unsigned int)(B_ - 1)) ? 1u : 0u;
    }
    __syncthreads();
    if (lastS) {
        if (tid < 128) {
            float v = partial[tid];
#pragma unroll
            for (int off = 32; off; off >>= 1) v += __shfl_down(v, off, 64);
            if ((tid & 63) == 0) redw[tid >> 6] = v;
        }
        __syncthreads();
        if (tid == 0) out[0] = redw[0] + redw[1];
    }
}

extern "C" void kernel_launch(void* const* d_in, const int* in_sizes, int n_in,
                              void* d_out, int out_size, void* d_ws, size_t ws_size,
                              hipStream_t stream)
{
    const int* seq = (const int*)d_in[0];
    const int* lab = (const int*)d_in[1];
    const float* emb    = (const float*)d_in[2];
    const float* w_ih_f = (const float*)d_in[3];
    const float* w_hh_f = (const float*)d_in[4];
    const float* b_ih_f = (const float*)d_in[5];
    const float* b_hh_f = (const float*)d_in[6];
    const float* w_ih_b = (const float*)d_in[7];
    const float* w_hh_b = (const float*)d_in[8];
    const float* b_ih_b = (const float*)d_in[9];
    const float* b_hh_b = (const float*)d_in[10];
    const float* w_out  = (const float*)d_in[11];
    const float* b_out  = (const float*)d_in[12];
    const float* start_t = (const float*)d_in[13];
    const float* end_t   = (const float*)d_in[14];
    const float* trans   = (const float*)d_in[15];

    char* ws = (char*)d_ws;
    const size_t xw_bytes   = (size_t)2 * B_ * S_ * G_ * sizeof(ushort_t);  // 134.2 MB
    const size_t wih_bytes  = (size_t)16384 * 16;                           // 256 KB
    const size_t bias_bytes = 1024 * sizeof(float);                         // 4 KB
    const size_t em_bytes   = (size_t)B_ * S_ * NL_ * sizeof(float);        // 2.36 MB

    ushort_t* xw      = (ushort_t*)ws;
    ushort_t* wihPack = (ushort_t*)(ws + xw_bytes);
    float* biasPack   = (float*)(ws + xw_bytes + wih_bytes);
    float* em_f       = (float*)(ws + xw_bytes + wih_bytes + bias_bytes);
    float* em_b       = (float*)(ws + xw_bytes + wih_bytes + bias_bytes + em_bytes);
    float* partial    = (float*)(ws + xw_bytes + wih_bytes + bias_bytes + 2 * em_bytes);
    unsigned int* ctr = (unsigned int*)(partial + B_);

    prep2_kernel<<<dim3(68), dim3(256), 0, stream>>>(w_ih_f, w_ih_b,
        b_ih_f, b_hh_f, b_ih_b, b_hh_b, wihPack, biasPack, ctr);
    xw2_kernel<<<dim3(2048), dim3(512), 0, stream>>>(seq, emb, wihPack, biasPack, xw);
    lstm_kernel<<<dim3(256), dim3(512), 0, stream>>>(xw, w_hh_f, w_hh_b,
        w_out, em_f, em_b);
    crf_kernel<<<dim3(B_), dim3(640), 0, stream>>>(seq, lab, em_f, em_b, b_out,
        start_t, end_t, trans, partial, ctr, (float*)d_out);
}

// Round 13
// 431.464 us; speedup vs baseline: 1.0073x; 1.0073x over previous
//
#include <hip/hip_runtime.h>
#include <hip/hip_bf16.h>

#define B_   128
#define S_   512
#define H_   128
#define G_   512   // 4*H
#define EMB_ 128
#define NL_  9

typedef __attribute__((ext_vector_type(8))) short bf16x8;
typedef __attribute__((ext_vector_type(4))) short bf16x4;
typedef __attribute__((ext_vector_type(4))) float f32x4;
typedef unsigned short ushort_t;

// LDS-only barrier: vmem ops stay in flight across it.
__device__ __forceinline__ void wg_bar() {
    asm volatile("s_waitcnt lgkmcnt(0)\n\ts_barrier" ::: "memory");
}

__device__ __forceinline__ float bfbits2f(short s) {
    unsigned int u = ((unsigned int)(unsigned short)s) << 16;
    return __builtin_bit_cast(float, u);
}
__device__ __forceinline__ short f2bf(float f) {
    unsigned int u = __builtin_bit_cast(unsigned int, f);
    u += 0x7FFFu + ((u >> 16) & 1u);
    return (short)(u >> 16);
}
__device__ __forceinline__ unsigned int pack2(float lo, float hi) {
    return (unsigned int)(unsigned short)f2bf(lo) | ((unsigned int)(unsigned short)f2bf(hi) << 16);
}
// raw transcendentals: avoid libm guard expansions.
__device__ __forceinline__ float exp2_(float x) {
    float r; asm("v_exp_f32 %0, %1" : "=v"(r) : "v"(x)); return r;
}
__device__ __forceinline__ float log2_(float x) {
    float r; asm("v_log_f32 %0, %1" : "=v"(r) : "v"(x)); return r;
}
__device__ __forceinline__ float max3_(float a, float b, float c) {
    float r; asm("v_max3_f32 %0, %1, %2, %3" : "=v"(r) : "v"(a), "v"(b), "v"(c)); return r;
}
__device__ __forceinline__ float tanh_(float x) {
    return 1.f - 2.f * __builtin_amdgcn_rcpf(1.f + exp2_(2.8853900817779268f * x));
}

// ---------------------------------------------------------------------------
// prep2: weights only (68 blocks, ~5 us). r9-verified + zeroes the crf
// completion counter each launch (graph-replay-safe).
// ---------------------------------------------------------------------------
__global__ __launch_bounds__(256)
void prep2_kernel(const float* __restrict__ w_ih_f, const float* __restrict__ w_ih_b,
                  const float* __restrict__ b_ih_f, const float* __restrict__ b_hh_f,
                  const float* __restrict__ b_ih_b, const float* __restrict__ b_hh_b,
                  ushort_t* __restrict__ wihPack, float* __restrict__ biasPack,
                  unsigned int* __restrict__ ctr)
{
    const int bid = blockIdx.x, tid = threadIdx.x;
    if (bid < 64) {
        int f = bid * 256 + tid;                  // 0..16383
        int lane = f & 63;
        int nt  = (f >> 6) & 3;
        int ks  = (f >> 8) & 3;
        int wv8 = (f >> 10) & 7;
        int dirq = (f >> 13) & 1;
        int n16 = lane & 15, quad = lane >> 4;
        const float* w = dirq ? w_ih_b : w_ih_f;
        int col = nt * 128 + wv8 * 16 + n16;
        const float* p = w + col * EMB_ + ks * 32 + quad * 8;
        bf16x8 r;
#pragma unroll
        for (int j = 0; j < 8; j++) r[j] = f2bf(p[j]);
        size_t addr = ((size_t)dirq * 8192 + wv8 * 1024 + ks * 256 + nt * 64 + lane) * 8;
        *(bf16x8*)(wihPack + addr) = r;
    } else {
        if (bid == 64 && tid == 0) *ctr = 0u;
        int idx = (bid - 64) * 256 + tid;
        if (idx < 1024) {
            int nt  = idx & 3;
            int n16 = (idx >> 2) & 15;
            int wv8 = (idx >> 6) & 7;
            int dirq = (idx >> 9) & 1;
            const float* bi = dirq ? b_ih_b : b_ih_f;
            const float* bh = dirq ? b_hh_b : b_hh_f;
            int col = nt * 128 + wv8 * 16 + n16;
            biasPack[idx] = bi[col] + bh[col];
        }
    }
}

// ---------------------------------------------------------------------------
// xw2: slim xw pre-pass, TILED: 512 blocks x 4 tiles of 32 t. Weight/bias
// prologue amortized 4x (was per-32-t block); at 512 blocks 2 blocks can
// co-reside per CU (LDS 17 KB) so staging overlaps compute. Math identical
// to r9-verified xw2.
// Output layout (ushorts): xw[((dir*128 + b)*512 + t)*512 + u*4 + nt].
// ---------------------------------------------------------------------------
__global__ __launch_bounds__(512, 1)
void xw2_kernel(const int* __restrict__ seq, const float* __restrict__ emb,
                const ushort_t* __restrict__ wihPack, const float* __restrict__ biasPack,
                ushort_t* __restrict__ xw)
{
    __shared__ bf16x8 ldsX[64 * 17];

    const int tid  = threadIdx.x;
    const int wv   = tid >> 6;
    const int lane = tid & 63;
    const int n16  = tid & 15;
    const int quad = (tid & 63) >> 4;
    const int dir  = blockIdx.x >> 8;          // 512 blocks
    const int rem  = blockIdx.x & 255;
    const int pair = rem >> 2;                 // 0..63
    const int tseg = (rem & 3) * 128;          // t-segment base

    // pre-packed weight fragments + fused biases (once per block)
    bf16x8 bfrag[4][4];
    float  bias[4];
    {
        const ushort_t* wb = wihPack + ((size_t)dir * 8192 + (size_t)wv * 1024 + lane) * 8;
#pragma unroll
        for (int nt = 0; nt < 4; nt++) {
            bias[nt] = biasPack[((dir * 8 + wv) * 16 + n16) * 4 + nt];
#pragma unroll
            for (int ks = 0; ks < 4; ks++)
                bfrag[nt][ks] = *(const bf16x8*)(wb + (ks * 256 + nt * 64) * 8);
        }
    }

    const size_t plane0 = (size_t)(dir * 128 + 2 * pair);
    const int srow = tid >> 3, spart = tid & 7;
    const int sb = 2 * pair + (srow >> 5);
    const int srt = srow >> 4, srr = srow & 15;

#pragma unroll 1
    for (int tt = 0; tt < 4; tt++) {
        const int tb = tseg + tt * 32;
        __syncthreads();   // previous tile's ldsX reads complete
        // stage 64 rows: rows 0..31 chain0 (b=2*pair), rows 32..63 chain1
        {
            int t = tb + (srow & 31);
            int tok = seq[sb * S_ + t];
            const float* ep = emb + (size_t)tok * EMB_ + spart * 16;
#pragma unroll
            for (int h = 0; h < 2; h++) {
                float4 a = *(const float4*)(ep + h * 8);
                float4 b4 = *(const float4*)(ep + h * 8 + 4);
                bf16x8 fr;
                fr[0] = f2bf(a.x); fr[1] = f2bf(a.y); fr[2] = f2bf(a.z); fr[3] = f2bf(a.w);
                fr[4] = f2bf(b4.x); fr[5] = f2bf(b4.y); fr[6] = f2bf(b4.z); fr[7] = f2bf(b4.w);
                ldsX[(srt * 16 + spart * 2 + h) * 17 + srr] = fr;
            }
        }
        __syncthreads();

#pragma unroll
        for (int half = 0; half < 2; half++) {
            // chain0 tile = half, chain1 tile = half+2
            f32x4 accA[4], accB[4];
            bf16x8 afA[4], afB[4];
#pragma unroll
            for (int ks = 0; ks < 4; ks++) {
                afA[ks] = ldsX[(half * 16 + ks * 4 + quad) * 17 + n16];
                afB[ks] = ldsX[((half + 2) * 16 + ks * 4 + quad) * 17 + n16];
            }
#pragma unroll
            for (int nt = 0; nt < 4; nt++) {
                f32x4 a = {bias[nt], bias[nt], bias[nt], bias[nt]};
                accA[nt] = a; accB[nt] = a;
#pragma unroll
                for (int ks = 0; ks < 4; ks++) {
                    accA[nt] = __builtin_amdgcn_mfma_f32_16x16x32_bf16(afA[ks], bfrag[nt][ks], accA[nt], 0, 0, 0);
                    accB[nt] = __builtin_amdgcn_mfma_f32_16x16x32_bf16(afB[ks], bfrag[nt][ks], accB[nt], 0, 0, 0);
                }
            }
            const int u = wv * 16 + n16;
#pragma unroll
            for (int r = 0; r < 4; r++) {
                int t = tb + half * 16 + quad * 4 + r;
                int2 iv0, iv1;
                iv0.x = (int)pack2(accA[0][r], accA[1][r]);
                iv0.y = (int)pack2(accA[2][r], accA[3][r]);
                iv1.x = (int)pack2(accB[0][r], accB[1][r]);
                iv1.y = (int)pack2(accB[2][r], accB[3][r]);
                *(int2*)(xw + ((plane0 * S_ + t) * 128 + u) * 4) = iv0;
                *(int2*)(xw + (((plane0 + 1) * S_ + t) * 128 + u) * 4) = iv1;
            }
        }
    }
}

// ---------------------------------------------------------------------------
// Recurrent LSTM: 8 waves/chain, r11-verified STEPK (serial chains,
// absmax 0.0). 2 waves/SIMD, single barrier per step.
// ---------------------------------------------------------------------------
#define STEPK(k)                                                                   \
  {                                                                                \
    if ((k) == 0 && s4 == 0 && m < 31) {                                           \
      const ushort_t* gp = xwp + (size_t)(dir ? (S_ - 32 - m16) : (m16 + 16)) * 512; \
      sA = *(const int4*)(gp + tid * 8);                                           \
      sB = *(const int4*)(gp + 4096 + tid * 8);                                    \
    }                                                                              \
    bf16x8 af0 = hbuf[(k) & 1][0 * 4 + quad];                                      \
    bf16x8 af1 = hbuf[(k) & 1][1 * 4 + quad];                                      \
    bf16x8 af2 = hbuf[(k) & 1][2 * 4 + quad];                                      \
    bf16x8 af3 = hbuf[(k) & 1][3 * 4 + quad];                                      \
    const int KE = s4x4 + (k);                                                     \
    const int slot = dir ? (15 - KE) : KE;                                         \
    bf16x4 xvg = *(const bf16x4*)(xwS + (m & 1) * 8192 + slot * 512 + uu * 4);     \
    if ((k) == 0 && s4 == 2 && m < 31) {                                           \
      int4* dst = (int4*)(xwL + (((m & 1) ^ 1) * 1024));                           \
      dst[tid] = sA; dst[512 + tid] = sB;                                          \
    }                                                                              \
    if ((k) == 1 && s4 == 0 && m >= 1 && wv == 7 && lane < 36) {                   \
      int a0 = dir ? (S_ - m16) : (m16 - 16);                                      \
      float4 fv = *(const float4*)(emL + (a0 & 31) * 9 + lane * 4);                \
      *(float4*)(emdir + (size_t)b * (S_ * NL_) + a0 * NL_ + lane * 4) = fv;       \
    }                                                                              \
    f32x4 aA0 = __builtin_amdgcn_mfma_f32_16x16x32_bf16(af0, bfrag[0][0], ZACC, 0, 0, 0); \
    f32x4 aA1 = __builtin_amdgcn_mfma_f32_16x16x32_bf16(af0, bfrag[1][0], ZACC, 0, 0, 0); \
    f32x4 aA2 = __builtin_amdgcn_mfma_f32_16x16x32_bf16(af0, bfrag[2][0], ZACC, 0, 0, 0); \
    f32x4 aA3 = __builtin_amdgcn_mfma_f32_16x16x32_bf16(af0, bfrag[3][0], ZACC, 0, 0, 0); \
    aA0 = __builtin_amdgcn_mfma_f32_16x16x32_bf16(af1, bfrag[0][1], aA0, 0, 0, 0); \
    aA1 = __builtin_amdgcn_mfma_f32_16x16x32_bf16(af1, bfrag[1][1], aA1, 0, 0, 0); \
    aA2 = __builtin_amdgcn_mfma_f32_16x16x32_bf16(af1, bfrag[2][1], aA2, 0, 0, 0); \
    aA3 = __builtin_amdgcn_mfma_f32_16x16x32_bf16(af1, bfrag[3][1], aA3, 0, 0, 0); \
    aA0 = __builtin_amdgcn_mfma_f32_16x16x32_bf16(af2, bfrag[0][2], aA0, 0, 0, 0); \
    aA1 = __builtin_amdgcn_mfma_f32_16x16x32_bf16(af2, bfrag[1][2], aA1, 0, 0, 0); \
    aA2 = __builtin_amdgcn_mfma_f32_16x16x32_bf16(af2, bfrag[2][2], aA2, 0, 0, 0); \
    aA3 = __builtin_amdgcn_mfma_f32_16x16x32_bf16(af2, bfrag[3][2], aA3, 0, 0, 0); \
    aA0 = __builtin_amdgcn_mfma_f32_16x16x32_bf16(af3, bfrag[0][3], aA0, 0, 0, 0); \
    aA1 = __builtin_amdgcn_mfma_f32_16x16x32_bf16(af3, bfrag[1][3], aA1, 0, 0, 0); \
    aA2 = __builtin_amdgcn_mfma_f32_16x16x32_bf16(af3, bfrag[2][3], aA2, 0, 0, 0); \
    aA3 = __builtin_amdgcn_mfma_f32_16x16x32_bf16(af3, bfrag[3][3], aA3, 0, 0, 0); \
    {                                                                              \
      float gi = aA0[0] + bfbits2f(xvg[0]);                                        \
      float gf = aA1[0] + bfbits2f(xvg[1]);                                        \
      float gg = aA2[0] + bfbits2f(xvg[2]);                                        \
      float go = aA3[0] + bfbits2f(xvg[3]);                                        \
      float Af = exp2_(-1.4426950408889634f * gf);                                 \
      float Bi = exp2_(-1.4426950408889634f * gi);                                 \
      float Cg = exp2_(2.8853900817779268f * gg);                                  \
      float Fo = exp2_(-1.4426950408889634f * go);                                 \
      float oA = 1.f + Af, oB = 1.f + Bi, oC = 1.f + Cg;                           \
      float P = oB * oC;                                                           \
      float numer = cst * P + oA * (Cg - 1.f);                                     \
      cst = numer * __builtin_amdgcn_rcpf(oA * P);                                 \
      float hv = tanh_(cst) * __builtin_amdgcn_rcpf(1.f + Fo);                     \
      if (quad == 0) *(((k) & 1) ? hw0 : hw1) = f2bf(hv);                          \
    }                                                                              \
    if (wv == 0) {                                                                 \
      f32x4 accE = __builtin_amdgcn_mfma_f32_16x16x32_bf16(af0, bfragE[0], ZACC, 0, 0, 0); \
      accE = __builtin_amdgcn_mfma_f32_16x16x32_bf16(af1, bfragE[1], accE, 0, 0, 0); \
      accE = __builtin_amdgcn_mfma_f32_16x16x32_bf16(af2, bfragE[2], accE, 0, 0, 0); \
      accE = __builtin_amdgcn_mfma_f32_16x16x32_bf16(af3, bfragE[3], accE, 0, 0, 0); \
      if (quad == 0 && n16 < NL_ && (m16 + KE) >= 1) {                             \
        int tprev = dir ? (S_ - (m16 + KE)) : (m16 + KE - 1);                      \
        emL[(tprev & 31) * 9 + n16] = accE[0];                                     \
      }                                                                            \
    }                                                                              \
    wg_bar();                                                                      \
  }

__global__ __launch_bounds__(512, 1)
void lstm_kernel(const ushort_t* __restrict__ xw,
                 const float* __restrict__ w_hh_f, const float* __restrict__ w_hh_b,
                 const float* __restrict__ w_out,
                 float* __restrict__ em_f, float* __restrict__ em_b)
{
    __shared__ bf16x8 xwL[2 * 1024];           // 32 KB: [buf][t*512 + u*4 + nt] ushorts
    __shared__ bf16x8 hbuf[2][16];             // 512 B, double-buffered h (128 bf16/buf)
    __shared__ __align__(16) float emL[32 * NL_];  // 1152 B: [slot][label]

    const int tid  = threadIdx.x;
    const int wv   = tid >> 6;                 // 8 waves
    const int lane = tid & 63;
    const int n16  = tid & 15;
    const int quad = (tid & 63) >> 4;
    const int dir  = blockIdx.x >> 7;
    const int b    = blockIdx.x & 127;

    const int uu = wv * 16 + n16;              // unit owned by this lane (quads redundant)

    // per-lane h-write pointers (buf0/buf1); writer is quad 0
    short* hw0 = ((short*)hbuf) + uu;
    short* hw1 = ((short*)hbuf) + 128 + uu;
    const short* xwS = (const short*)xwL;

    const f32x4 ZACC = {0.f, 0.f, 0.f, 0.f};

    const float* whh = dir ? w_hh_b : w_hh_f;
    float* emdir = dir ? em_b : em_f;

    // W_hh fragments: bfrag[gate][ks]; gate col = nt*128 + wv*16 + n16
    bf16x8 bfrag[4][4];
#pragma unroll
    for (int nt = 0; nt < 4; nt++) {
        int col = nt * 128 + wv * 16 + n16;
#pragma unroll
        for (int ks = 0; ks < 4; ks++) {
            const float* p = whh + col * H_ + ks * 32 + quad * 8;
            bf16x8 fr;
#pragma unroll
            for (int j = 0; j < 8; j++) fr[j] = f2bf(p[j]);
            bfrag[nt][ks] = fr;
        }
    }
    bf16x8 bfragE[4];
#pragma unroll
    for (int ks = 0; ks < 4; ks++) {
        bf16x8 fr = {0, 0, 0, 0, 0, 0, 0, 0};
        if (n16 < NL_) {
            const float* p = w_out + n16 * 256 + dir * 128 + ks * 32 + quad * 8;
#pragma unroll
            for (int j = 0; j < 8; j++) fr[j] = f2bf(p[j]);
        }
        bfragE[ks] = fr;
    }

    if (tid < 64) ((int*)hbuf)[tid] = 0;   // zero h buffer 0 (256 B)

    const ushort_t* xwp = xw + (size_t)(dir * 128 + b) * ((size_t)S_ * 512);
    // pre-stage block 0 (16 KB): 2 x int4 per thread
    {
        const ushort_t* gp = xwp + (size_t)(dir ? (S_ - 16) : 0) * 512;
        int4 a0 = *(const int4*)(gp + tid * 8);
        int4 a1 = *(const int4*)(gp + 4096 + tid * 8);
        int4* dst = (int4*)xwL;
        dst[tid] = a0; dst[512 + tid] = a1;
    }

    float cst = 0.f;
    int4 sA, sB;
    wg_bar();

#pragma unroll 1
    for (int m = 0; m < 32; m++) {
        const int m16 = m << 4;
#pragma unroll 1
        for (int s4 = 0; s4 < 4; s4++) {
            const int s4x4 = s4 << 2;
            STEPK(0) STEPK(1) STEPK(2) STEPK(3)
        }
    }

    // final emission (h after step 512, in buf0), then tail flush
    if (wv == 0) {
        bf16x8 af0 = hbuf[0][0 * 4 + quad];
        bf16x8 af1 = hbuf[0][1 * 4 + quad];
        bf16x8 af2 = hbuf[0][2 * 4 + quad];
        bf16x8 af3 = hbuf[0][3 * 4 + quad];
        f32x4 accE = __builtin_amdgcn_mfma_f32_16x16x32_bf16(af0, bfragE[0], ZACC, 0, 0, 0);
        accE = __builtin_amdgcn_mfma_f32_16x16x32_bf16(af1, bfragE[1], accE, 0, 0, 0);
        accE = __builtin_amdgcn_mfma_f32_16x16x32_bf16(af2, bfragE[2], accE, 0, 0, 0);
        accE = __builtin_amdgcn_mfma_f32_16x16x32_bf16(af3, bfragE[3], accE, 0, 0, 0);
        if (quad == 0 && n16 < NL_) {
            int tprev = dir ? 0 : (S_ - 1);
            emL[(tprev & 31) * 9 + n16] = accE[0];
        }
    }
    wg_bar();
    if (wv == 7 && lane < 36) {
        int a0 = dir ? 0 : (S_ - 16);
        float4 fv = *(const float4*)(emL + (a0 & 31) * 9 + lane * 4);
        *(float4*)(emdir + (size_t)b * (S_ * NL_) + a0 * NL_ + lane * 4) = fv;
    }
}

// ---------------------------------------------------------------------------
// CRF with chunked parallel scan + in-kernel final reduction (last-block
// pattern, r12-verified). Counter zeroed by prep2 each launch; %128 guard.
// ---------------------------------------------------------------------------
__global__ __launch_bounds__(640, 1)
void crf_kernel(const int* __restrict__ seq, const int* __restrict__ lab,
                const float* __restrict__ em_f, const float* __restrict__ em_b,
                const float* __restrict__ b_out,
                const float* __restrict__ start_t, const float* __restrict__ end_t,
                const float* __restrict__ trans, float* __restrict__ partial,
                unsigned int* __restrict__ ctr, float* __restrict__ out)
{
    __shared__ float emS[S_ * NL_];
    __shared__ float transS[NL_ * NL_];
    __shared__ float stS[NL_], enS[NL_];
    __shared__ unsigned char maskS[S_];
    __shared__ float MS[7 * 81];
    __shared__ float vS[NL_];
    __shared__ float redw[10];
    __shared__ int   redl[10];
    __shared__ unsigned int lastS;

    const int b = blockIdx.x, tid = threadIdx.x;
    const size_t base = (size_t)b * S_ * NL_;
    const float L2E = 1.4426950408889634f, LN2 = 0.6931471805599453f;

    for (int q = tid; q < S_ * NL_; q += 640)
        emS[q] = em_f[base + q] + em_b[base + q] + b_out[q % NL_];
    if (tid < NL_ * NL_) transS[tid] = trans[tid];
    if (tid < NL_) { stS[tid] = start_t[tid]; enS[tid] = end_t[tid]; }
    if (tid < S_) maskS[tid] = (seq[b * S_ + tid] != 0);
    __syncthreads();

    float np = 0.f; int myc = 0;
    if (tid < S_) {
        myc = maskS[tid];
        if (tid >= 1 && maskS[tid]) {
            int lp = lab[b * S_ + tid - 1], lc = lab[b * S_ + tid];
            np = transS[lp * NL_ + lc] + emS[tid * NL_ + lc];
        }
    }
#pragma unroll
    for (int off = 32; off; off >>= 1) {
        np  += __shfl_down(np, off, 64);
        myc += __shfl_down(myc, off, 64);
    }
    if ((tid & 63) == 0) { redw[tid >> 6] = np; redl[tid >> 6] = myc; }

    const int w = tid >> 6, l = tid & 63;
    const int lg = l / 9;
    const int g  = w * 7 + lg;
    const bool sact = (lg < 7) && (g < 64);
    const int jj = sact ? (l - lg * 9) : 0;
    const int gb = sact ? lg * 9 : 0;
    float Tc[NL_];
#pragma unroll
    for (int i = 0; i < NL_; i++) Tc[i] = transS[i * NL_ + jj];
    float sc; int tbeg, tend, cN = 0, iN = 0;
    if (sact && g == 0) {
        sc = stS[jj] + emS[jj];
        tbeg = 1; tend = 64;
    } else if (sact) {
        cN = 1 + (g - 1) / 9; iN = (g - 1) % 9;
        sc = (jj == iN) ? 0.f : -1e30f;
        tbeg = cN * 64; tend = tbeg + 64;
    } else {
        sc = -1e30f; tbeg = 448; tend = 512;
    }
    for (int t = tbeg; t < tend; t++) {
        float emv = emS[t * NL_ + jj];
        float a[NL_];
#pragma unroll
        for (int i = 0; i < NL_; i++) a[i] = __shfl(sc, gb + i, 64) + Tc[i];
        float m = max3_(max3_(a[0], a[1], a[2]), max3_(a[3], a[4], a[5]),
                        max3_(a[6], a[7], a[8]));
        float e[NL_];
#pragma unroll
        for (int i = 0; i < NL_; i++) e[i] = exp2_((a[i] - m) * L2E);
        float sum = ((e[0] + e[1]) + (e[2] + e[3])) + ((e[4] + e[5]) + (e[6] + e[7])) + e[8];
        float nxt = emv + m + LN2 * log2_(sum);
        sc = maskS[t] ? nxt : sc;
    }
    if (sact) {
        if (g == 0) vS[jj] = sc;
        else MS[(cN - 1) * 81 + iN * NL_ + jj] = sc;
    }
    __syncthreads();

    if (tid < 64) {
        const int j = (tid < NL_) ? tid : (NL_ - 1);
        float v = vS[j];
        for (int c = 1; c < 8; c++) {
            float a[NL_];
#pragma unroll
            for (int i = 0; i < NL_; i++)
                a[i] = __shfl(v, i, 64) + MS[(c - 1) * 81 + i * NL_ + j];
            float m = max3_(max3_(a[0], a[1], a[2]), max3_(a[3], a[4], a[5]),
                            max3_(a[6], a[7], a[8]));
            float e[NL_];
#pragma unroll
            for (int i = 0; i < NL_; i++) e[i] = exp2_((a[i] - m) * L2E);
            float sum = ((e[0] + e[1]) + (e[2] + e[3])) + ((e[4] + e[5]) + (e[6] + e[7])) + e[8];
            v = m + LN2 * log2_(sum);
        }
        v += enS[j];
        float mm = -1e30f, av[NL_];
#pragma unroll
        for (int i = 0; i < NL_; i++) { float vi = __shfl(v, i, 64); av[i] = vi; mm = fmaxf(mm, vi); }
        float ss = 0.f;
#pragma unroll
        for (int i = 0; i < NL_; i++) ss += exp2_((av[i] - mm) * L2E);
        if (tid == 0) {
            float num = 0.f; int len = 0;
#pragma unroll
            for (int ww = 0; ww < 10; ww++) { num += redw[ww]; len += redl[ww]; }
            int l0 = lab[b * S_];
            int ll = lab[b * S_ + len - 1];
            num += stS[l0] + emS[l0] + enS[ll];
            partial[b] = (mm + LN2 * log2_(ss)) - num;
        }
    }
    __syncthreads();

    // last-block final reduction
    if (tid == 0) {
        __threadfence();
        unsigned int v = atomicAdd(ctr, 1u);
        lastS = ((v % (unsigned int)B_) == (unsigned int)(B_ - 1)) ? 1u : 0u;
    }
    __syncthreads();
    if (lastS) {
        if (tid < 128) {
            float v = partial[tid];
#pragma unroll
            for (int off = 32; off; off >>= 1) v += __shfl_down(v, off, 64);
            if ((tid & 63) == 0) redw[tid >> 6] = v;
        }
        __syncthreads();
        if (tid == 0) out[0] = redw[0] + redw[1];
    }
}

extern "C" void kernel_launch(void* const* d_in, const int* in_sizes, int n_in,
                              void* d_out, int out_size, void* d_ws, size_t ws_size,
                              hipStream_t stream)
{
    const int* seq = (const int*)d_in[0];
    const int* lab = (const int*)d_in[1];
    const float* emb    = (const float*)d_in[2];
    const float* w_ih_f = (const float*)d_in[3];
    const float* w_hh_f = (const float*)d_in[4];
    const float* b_ih_f = (const float*)d_in[5];
    const float* b_hh_f = (const float*)d_in[6];
    const float* w_ih_b = (const float*)d_in[7];
    const float* w_hh_b = (const float*)d_in[8];
    const float* b_ih_b = (const float*)d_in[9];
    const float* b_hh_b = (const float*)d_in[10];
    const float* w_out  = (const float*)d_in[11];
    const float* b_out  = (const float*)d_in[12];
    const float* start_t = (const float*)d_in[13];
    const float* end_t   = (const float*)d_in[14];
    const float* trans   = (const float*)d_in[15];

    char* ws = (char*)d_ws;
    const size_t xw_bytes   = (size_t)2 * B_ * S_ * G_ * sizeof(ushort_t);  // 134.2 MB
    const size_t wih_bytes  = (size_t)16384 * 16;                           // 256 KB
    const size_t bias_bytes = 1024 * sizeof(float);                         // 4 KB
    const size_t em_bytes   = (size_t)B_ * S_ * NL_ * sizeof(float);        // 2.36 MB

    ushort_t* xw      = (ushort_t*)ws;
    ushort_t* wihPack = (ushort_t*)(ws + xw_bytes);
    float* biasPack   = (float*)(ws + xw_bytes + wih_bytes);
    float* em_f       = (float*)(ws + xw_bytes + wih_bytes + bias_bytes);
    float* em_b       = (float*)(ws + xw_bytes + wih_bytes + bias_bytes + em_bytes);
    float* partial    = (float*)(ws + xw_bytes + wih_bytes + bias_bytes + 2 * em_bytes);
    unsigned int* ctr = (unsigned int*)(partial + B_);

    prep2_kernel<<<dim3(68), dim3(256), 0, stream>>>(w_ih_f, w_ih_b,
        b_ih_f, b_hh_f, b_ih_b, b_hh_b, wihPack, biasPack, ctr);
    xw2_kernel<<<dim3(512), dim3(512), 0, stream>>>(seq, emb, wihPack, biasPack, xw);
    lstm_kernel<<<dim3(256), dim3(512), 0, stream>>>(xw, w_hh_f, w_hh_b,
        w_out, em_f, em_b);
    crf_kernel<<<dim3(B_), dim3(640), 0, stream>>>(seq, lab, em_f, em_b, b_out,
        start_t, end_t, trans, partial, ctr, (float*)d_out);
}